// Round 5
// baseline (1031.304 us; speedup 1.0000x reference)
//
#include <hip/hip_runtime.h>
#include <math.h>

#define N_NODES 3000
#define F_INF 5
#define HF 64
#define NE 30000

typedef short bf16x8 __attribute__((ext_vector_type(8)));
typedef float f32x4 __attribute__((ext_vector_type(4)));

// ---------------- device helpers ----------------
static __device__ __forceinline__ float gelu_f(float v) {
    return 0.5f * v * (1.0f + erff(v * 0.70710678118654752f));
}
static __device__ __forceinline__ unsigned short f2bf(float f) {
    union { float f; unsigned u; } v; v.f = f;
    return (unsigned short)(v.u >> 16);   // truncation: exact for small integers
}

// ---------------- BatchNorm1d (training stats, biased var) ----------------
__global__ void k_bn(const float* __restrict__ x, const float* __restrict__ g,
                     const float* __restrict__ b, float* __restrict__ xn, int n) {
    int f = blockIdx.x;
    int tid = threadIdx.x;
    __shared__ float red[256];
    float s = 0.f;
    for (int v = tid; v < n; v += 256) s += x[v * F_INF + f];
    red[tid] = s; __syncthreads();
    for (int o = 128; o > 0; o >>= 1) { if (tid < o) red[tid] += red[tid + o]; __syncthreads(); }
    float mu = red[0] / n;
    __syncthreads();
    float sq = 0.f;
    for (int v = tid; v < n; v += 256) { float d = x[v * F_INF + f] - mu; sq += d * d; }
    red[tid] = sq; __syncthreads();
    for (int o = 128; o > 0; o >>= 1) { if (tid < o) red[tid] += red[tid + o]; __syncthreads(); }
    float rs = 1.0f / sqrtf(red[0] / n + 1e-5f);
    float gg = g[f], bb = b[f];
    for (int v = tid; v < n; v += 256)
        xn[v * F_INF + f] = (x[v * F_INF + f] - mu) * rs * gg + bb;
}

// ---------------- dense adjacency build (unit weights) ----------------
__global__ void k_adj(const int* __restrict__ ei, float* __restrict__ A, int n) {
    int e = blockIdx.x * blockDim.x + threadIdx.x;
    if (e >= NE) return;
    atomicAdd(&A[(size_t)ei[e] * n + ei[NE + e]], 1.0f);
}

// ---------------- degrees ----------------
__global__ void k_edeg(const int* __restrict__ ei, float* __restrict__ degw,
                       float* __restrict__ dself) {
    int e = blockIdx.x * blockDim.x + threadIdx.x;
    if (e >= NE) return;
    int s = ei[e], d = ei[NE + e];
    atomicAdd(&degw[d], 1.0f);
    if (s == d) atomicAdd(&dself[d], 1.0f);
}

__global__ void k_fdeg(const int* __restrict__ ei, const float* __restrict__ ea,
                       float* __restrict__ degw, float* __restrict__ dself) {
    int e = blockIdx.x * blockDim.x + threadIdx.x;
    if (e >= NE) return;
    int s = ei[e], d = ei[NE + e];
    float w = ea[e];
    atomicAdd(&degw[d], w);
    if (s == d) atomicAdd(&dself[d], w);
}

// dinv from edge-accumulated degw/dself
__global__ void k_dinv(const float* __restrict__ degw, const float* __restrict__ dself,
                       int n, float* __restrict__ dinv, float* __restrict__ selfw) {
    int j = blockIdx.x * 256 + threadIdx.x;
    if (j >= n) return;
    float dl = (dself[j] == 0.f) ? 1.f : 0.f;
    float deg = degw[j] + dl;
    float di = (deg > 0.f) ? (1.0f / sqrtf(deg)) : 0.f;
    dinv[j] = di;
    selfw[j] = dl * di;
}

// dinv for dense A (degw pre-accumulated by pgemm epilogue): reads diagonal directly
__global__ void k_dinv_dense(const float* __restrict__ degw, const float* __restrict__ A,
                             int n, float* __restrict__ dinv, float* __restrict__ selfw) {
    int j = blockIdx.x * 256 + threadIdx.x;
    if (j >= n) return;
    float dl = (A[(size_t)j * n + j] == 0.f) ? 1.f : 0.f;
    float deg = degw[j] + dl;
    float di = (deg > 0.f) ? (1.0f / sqrtf(deg)) : 0.f;
    dinv[j] = di;
    selfw[j] = dl * di;
}

// ---------------- Y = dinv[v] * (X @ W) ----------------
__global__ void k_xw(const float* __restrict__ X, const float* __restrict__ Wm,
                     const float* __restrict__ dinv, int n, int fin, int fout,
                     float* __restrict__ Y) {
    int t = blockIdx.x * blockDim.x + threadIdx.x;
    if (t >= n * fout) return;
    int v = t / fout, fo = t % fout;
    float s = 0.f;
    for (int fi = 0; fi < fin; ++fi) s += X[v * fin + fi] * Wm[fi * fout + fo];
    Y[t] = dinv[v] * s;
}

// ---------------- edge aggregation (A0-based GCNs, fout=64) ----------------
__global__ void k_eagg(const int* __restrict__ ei, const float* __restrict__ Y,
                       float* __restrict__ tmp) {
    int t = blockIdx.x * blockDim.x + threadIdx.x;
    if (t >= NE * HF) return;
    int e = t >> 6, f = t & 63;
    atomicAdd(&tmp[(size_t)ei[NE + e] * HF + f], Y[(size_t)ei[e] * HF + f]);
}

__global__ void k_gcn_fin(const float* __restrict__ tmp, const float* __restrict__ Y,
                          const float* __restrict__ dinv, const float* __restrict__ selfw,
                          const float* __restrict__ bias, float* __restrict__ out,
                          int n, int dogelu) {
    int t = blockIdx.x * blockDim.x + threadIdx.x;
    if (t >= n * HF) return;
    int v = t >> 6, f = t & 63;
    float val = dinv[v] * tmp[t] + selfw[v] * Y[t] + bias[f];
    if (dogelu) val = gelu_f(val);
    out[t] = val;
}

// ---------------- dense aggregation (pooled levels): out = dinv*(A^T@Y)+selfw*Y+b ----------
// 16-row x 64-col tile per block: grid cdiv(n,16) blocks (94 at n=1500) for occupancy.
// Per-element K-summation order identical to any sequential tiling (bit-stable).
__global__ void k_agg(const float* __restrict__ A, const float* __restrict__ Y,
                      const float* __restrict__ dinv, const float* __restrict__ selfw,
                      const float* __restrict__ bias, float* __restrict__ out,
                      int n, int dogelu) {
    __shared__ float As[16][17];   // [kk][ii]
    __shared__ float Bs[16][68];   // [kk][ff], row stride 68 floats (16B-aligned float4 slots)
    int i0 = blockIdx.x * 16;
    int tid = threadIdx.x;
    int tr = tid >> 4, tc = tid & 15;
    float acc[4] = {};
    for (int k0 = 0; k0 < n; k0 += 16) {
        {   // stage A: 16k x 16i (one element per thread)
            int kk = tid >> 4, ii = tid & 15;
            int gk = k0 + kk, gi = i0 + ii;
            As[kk][ii] = (gk < n && gi < n) ? A[(size_t)gk * n + gi] : 0.f;
        }
        {   // stage Y: 16k x 64f (float4 per thread)
            int kk = tid >> 4, f4 = (tid & 15) * 4;
            int gk = k0 + kk;
            if (gk < n) {
                float4 v = *(const float4*)&Y[(size_t)gk * HF + f4];
                *(float4*)&Bs[kk][f4] = v;
            } else {
                float4 z = {0.f, 0.f, 0.f, 0.f};
                *(float4*)&Bs[kk][f4] = z;
            }
        }
        __syncthreads();
#pragma unroll
        for (int kk = 0; kk < 16; ++kk) {
            float a = As[kk][tr];
#pragma unroll
            for (int w = 0; w < 4; ++w) acc[w] += a * Bs[kk][tc * 4 + w];
        }
        __syncthreads();
    }
    int i = i0 + tr;
    if (i < n) {
        float di = dinv[i], sw = selfw[i];
#pragma unroll
        for (int w = 0; w < 4; ++w) {
            int j = tc * 4 + w;
            float val = di * acc[w] + sw * Y[(size_t)i * HF + j] + bias[j];
            if (dogelu) val = gelu_f(val);
            out[(size_t)i * HF + j] = val;
        }
    }
}

// ---------------- TopK pooling: fused score + bitonic top-k (single block) ----------------
__global__ __launch_bounds__(1024) void k_score_topk(
    const float* __restrict__ h, const float* __restrict__ p, int n, int k, int size,
    float* __restrict__ score, int* __restrict__ perm) {
    __shared__ float s[4096];
    __shared__ int idx[4096];
    int tid = threadIdx.x;
    float pn = 0.f;
#pragma unroll
    for (int f = 0; f < HF; ++f) pn += p[f] * p[f];
    float rnorm = 1.0f / sqrtf(pn);
    for (int v = tid; v < n; v += 1024) {
        float dot = 0.f;
#pragma unroll
        for (int f = 0; f < HF; ++f) dot += h[v * HF + f] * p[f];
        float sc = tanhf(dot * rnorm);
        score[v] = sc;
        s[v] = sc;
        idx[v] = v;
    }
    for (int v = n + tid; v < size; v += 1024) { s[v] = -2.0f; idx[v] = v; }
    __syncthreads();
    for (int kk = 2; kk <= size; kk <<= 1) {
        for (int j = kk >> 1; j > 0; j >>= 1) {
            for (int i = tid; i < size; i += 1024) {
                int ixj = i ^ j;
                if (ixj > i) {
                    float s1 = s[i], s2 = s[ixj];
                    int i1 = idx[i], i2 = idx[ixj];
                    bool aBeforeB = (s1 > s2) || (s1 == s2 && i1 < i2);
                    bool up = ((i & kk) == 0);
                    bool sw = up ? (!aBeforeB) : aBeforeB;
                    if (sw) { s[i] = s2; s[ixj] = s1; idx[i] = i2; idx[ixj] = i1; }
                }
            }
            __syncthreads();
        }
    }
    for (int i = tid; i < k; i += 1024) perm[i] = idx[i];
}

__global__ void k_poolx(const float* __restrict__ h, const float* __restrict__ score,
                        const int* __restrict__ perm, int k, float* __restrict__ hp) {
    int t = blockIdx.x * blockDim.x + threadIdx.x;
    if (t >= k * HF) return;
    int i = t / HF, f = t % HF;
    int pi = perm[i];
    hp[t] = h[pi * HF + f] * score[pi];
}

// ---------------- bf16 gathers for the augment GEMM ----------------
// Rg[i*Kpad+m] = A[perm_i * nfull + m]  (row gather; float2 reads, ushort2 writes)
__global__ void k_gather_rg(const float* __restrict__ A, const int* __restrict__ perm,
                            int nfull, int M, int Kpad, unsigned short* __restrict__ Rg) {
    int t = blockIdx.x * blockDim.x + threadIdx.x;
    int kh = Kpad >> 1;
    if (t >= M * kh) return;
    int i = t / kh, m2 = (t - i * kh) * 2;
    const float* row = A + (size_t)perm[i] * nfull;
    float v0 = 0.f, v1 = 0.f;
    if (m2 + 1 < nfull) { float2 vv = *(const float2*)&row[m2]; v0 = vv.x; v1 = vv.y; }
    else if (m2 < nfull) { v0 = row[m2]; }
    unsigned pk = (unsigned)f2bf(v0) | ((unsigned)f2bf(v1) << 16);
    *(unsigned*)&Rg[(size_t)i * Kpad + m2] = pk;
}

// CgbT[j*Kpad+m] = A[m * nfull + perm_j] + 2*(m==perm_j)   (gather-transpose via LDS,
// +2S fold so the pgemm epilogue needs no adjacency gather). Zero-padded to Npad x Kpad.
__global__ __launch_bounds__(256) void k_gather_ct(
    const float* __restrict__ A, const int* __restrict__ perm,
    int nfull, int Nc, int Kpad, unsigned short* __restrict__ CgbT) {
    __shared__ float Ts[32][33];
    int j0 = blockIdx.x * 32, m0 = blockIdx.y * 32;
    int t = threadIdx.x;
    {   // read phase: m-major lanes, gathered columns of A
        int ml = t >> 3, jl4 = (t & 7) * 4;
        int m = m0 + ml;
#pragma unroll
        for (int e = 0; e < 4; ++e) {
            int j = j0 + jl4 + e;
            float v = 0.f;
            if (m < nfull && j < Nc) {
                int pj = perm[j];
                v = A[(size_t)m * nfull + pj];
                if (m == pj) v += 2.f;
            }
            Ts[jl4 + e][ml] = v;
        }
    }
    __syncthreads();
    {   // write phase: j-major lanes, coalesced ushort4 stores
        int jl = t >> 3, mq = (t & 7) * 4;
        unsigned lo = (unsigned)f2bf(Ts[jl][mq])     | ((unsigned)f2bf(Ts[jl][mq + 1]) << 16);
        unsigned hi = (unsigned)f2bf(Ts[jl][mq + 2]) | ((unsigned)f2bf(Ts[jl][mq + 3]) << 16);
        uint2 w; w.x = lo; w.y = hi;
        *(uint2*)&CgbT[(size_t)(j0 + jl) * Kpad + m0 + mq] = w;
    }
}

// ---------------- MFMA bf16 GEMM: C[i][j] = sum_m Rg[i][m]*CgbT[j][m]; diag=0 ----------------
// Exact: operands are small integers (bf16-exact), fp32 accumulate. +2A folded into CgbT.
// Epilogue also accumulates column sums (exact integers) into degw for gcn_norm.
__global__ __launch_bounds__(256) void k_pgemm_mfma(
    const unsigned short* __restrict__ Rg,    // M x Kpad (row-major)
    const unsigned short* __restrict__ CgbT,  // Npad x Kpad (row-major = B^T)
    float* __restrict__ C, int M, int Nc, int Kpad,
    float* __restrict__ degw) {
    __shared__ __align__(16) unsigned short As[64][40];
    __shared__ __align__(16) unsigned short Bs[64][40];
    int i0 = blockIdx.x * 64, j0 = blockIdx.y * 64;
    int tid = threadIdx.x;
    int lane = tid & 63, wid = tid >> 6;
    int wm = wid >> 1, wn = wid & 1;           // 2x2 wave grid, each wave 32x32
    f32x4 acc[2][2] = {};
    int r = lane & 15, kq = lane >> 4;
    int srow = tid >> 2, scq = (tid & 3) * 8;  // staging: 64 rows x 4 chunks of 8
    for (int k0 = 0; k0 < Kpad; k0 += 32) {
        int gi = i0 + srow;
        bf16x8 av = {0, 0, 0, 0, 0, 0, 0, 0};
        if (gi < M) av = *(const bf16x8*)&Rg[(size_t)gi * Kpad + k0 + scq];
        bf16x8 bv = *(const bf16x8*)&CgbT[(size_t)(j0 + srow) * Kpad + k0 + scq];
        *(bf16x8*)&As[srow][scq] = av;
        *(bf16x8*)&Bs[srow][scq] = bv;
        __syncthreads();
        bf16x8 a0 = *(const bf16x8*)&As[wm * 32 + r][kq * 8];
        bf16x8 a1 = *(const bf16x8*)&As[wm * 32 + 16 + r][kq * 8];
        bf16x8 b0 = *(const bf16x8*)&Bs[wn * 32 + r][kq * 8];
        bf16x8 b1 = *(const bf16x8*)&Bs[wn * 32 + 16 + r][kq * 8];
        acc[0][0] = __builtin_amdgcn_mfma_f32_16x16x32_bf16(a0, b0, acc[0][0], 0, 0, 0);
        acc[0][1] = __builtin_amdgcn_mfma_f32_16x16x32_bf16(a0, b1, acc[0][1], 0, 0, 0);
        acc[1][0] = __builtin_amdgcn_mfma_f32_16x16x32_bf16(a1, b0, acc[1][0], 0, 0, 0);
        acc[1][1] = __builtin_amdgcn_mfma_f32_16x16x32_bf16(a1, b1, acc[1][1], 0, 0, 0);
        __syncthreads();
    }
#pragma unroll
    for (int nj = 0; nj < 2; ++nj) {
        int j = j0 + wn * 32 + nj * 16 + r;              // col = lane&15
        float csum = 0.f;
#pragma unroll
        for (int mi = 0; mi < 2; ++mi)
#pragma unroll
            for (int reg = 0; reg < 4; ++reg) {
                int i = i0 + wm * 32 + mi * 16 + kq * 4 + reg;   // row = (lane>>4)*4+reg
                if (i < M && j < Nc) {
                    float v = acc[mi][nj][reg];
                    if (i == j) v = 0.f;
                    C[(size_t)i * Nc + j] = v;
                    csum += v;
                }
            }
        if (j < Nc && csum != 0.f) atomicAdd(&degw[j], csum);
    }
}

// ---------------- unpool (concat skip) ----------------
__global__ void k_concat(const float* __restrict__ res, float* __restrict__ c, int n) {
    int t = blockIdx.x * blockDim.x + threadIdx.x;
    if (t >= n * HF) return;
    int v = t / HF, f = t % HF;
    c[v * (2 * HF) + f] = res[t];
    c[v * (2 * HF) + HF + f] = 0.f;
}

__global__ void k_upscat(const float* __restrict__ h, const int* __restrict__ perm,
                         float* __restrict__ c, int k) {
    int t = blockIdx.x * blockDim.x + threadIdx.x;
    if (t >= k * HF) return;
    int i = t / HF, f = t % HF;
    c[perm[i] * (2 * HF) + HF + f] = h[t];
}

// ---------------- final edge-based GCN (fout=3) ----------------
__global__ void k_finit(const float* __restrict__ fb, const float* __restrict__ selfw,
                        const float* __restrict__ Y3, float* __restrict__ out, int n) {
    int t = blockIdx.x * blockDim.x + threadIdx.x;
    if (t >= n * 3) return;
    int j = t / 3, f = t % 3;
    out[t] = fb[f] + selfw[j] * Y3[t];
}

__global__ void k_fedge(const int* __restrict__ ei, const float* __restrict__ ea,
                        const float* __restrict__ dinv, const float* __restrict__ Y3,
                        float* __restrict__ out) {
    int e = blockIdx.x * blockDim.x + threadIdx.x;
    if (e >= NE) return;
    int s = ei[e], d = ei[NE + e];
    float c = ea[e] * dinv[d];
    atomicAdd(&out[d * 3 + 0], c * Y3[s * 3 + 0]);
    atomicAdd(&out[d * 3 + 1], c * Y3[s * 3 + 1]);
    atomicAdd(&out[d * 3 + 2], c * Y3[s * 3 + 2]);
}

// ================= host orchestration =================
static inline int cdiv(int a, int b) { return (a + b - 1) / b; }

static void gcn_dense(hipStream_t st, const float* A, int n, const float* X, int fin,
                      const float* Wm, const float* bias, const float* dinv,
                      const float* selfw, float* Y, float* out, bool gelu) {
    k_xw<<<cdiv(n * HF, 256), 256, 0, st>>>(X, Wm, dinv, n, fin, HF, Y);
    k_agg<<<cdiv(n, 16), 256, 0, st>>>(A, Y, dinv, selfw, bias, out, n, gelu ? 1 : 0);
}

static void gcn_edge(hipStream_t st, const int* ei, const float* X, int fin,
                     const float* Wm, const float* bias, const float* dinv,
                     const float* selfw, float* Y, float* tmp, float* out, bool gelu) {
    k_xw<<<cdiv(N_NODES * HF, 256), 256, 0, st>>>(X, Wm, dinv, N_NODES, fin, HF, Y);
    hipMemsetAsync(tmp, 0, N_NODES * HF * sizeof(float), st);
    k_eagg<<<cdiv(NE * HF, 256), 256, 0, st>>>(ei, Y, tmp);
    k_gcn_fin<<<cdiv(N_NODES * HF, 256), 256, 0, st>>>(tmp, Y, dinv, selfw, bias, out,
                                                       N_NODES, gelu ? 1 : 0);
}

extern "C" void kernel_launch(void* const* d_in, const int* in_sizes, int n_in,
                              void* d_out, int out_size, void* d_ws, size_t ws_size,
                              hipStream_t stream) {
    const float* x   = (const float*)d_in[0];
    const int*   ei  = (const int*)d_in[1];
    const float* ea  = (const float*)d_in[2];
    const float* bng = (const float*)d_in[3];
    const float* bnb = (const float*)d_in[4];
    const float* dw0 = (const float*)d_in[5];
    const float* db0 = (const float*)d_in[6];
    const float* dw1 = (const float*)d_in[7];
    const float* db1 = (const float*)d_in[8];
    const float* dw2 = (const float*)d_in[9];
    const float* db2 = (const float*)d_in[10];
    const float* dw3 = (const float*)d_in[11];
    const float* db3 = (const float*)d_in[12];
    const float* p1  = (const float*)d_in[13];
    const float* p2  = (const float*)d_in[14];
    const float* p3  = (const float*)d_in[15];
    const float* uw1 = (const float*)d_in[16];
    const float* ub1 = (const float*)d_in[17];
    const float* uw2 = (const float*)d_in[18];
    const float* ub2 = (const float*)d_in[19];
    const float* uw3 = (const float*)d_in[20];
    const float* ub3 = (const float*)d_in[21];
    const float* fw  = (const float*)d_in[22];
    const float* fb  = (const float*)d_in[23];
    float* outp = (float*)d_out;

    // workspace layout (floats, 16B-aligned slots)
    float* W = (float*)d_ws;
    size_t o = 0;
    auto alloc = [&](size_t cnt) { float* p = W + o; o += (cnt + 3) & ~size_t(3); return p; };
    float* As0   = alloc(9000000);
    float* As1   = alloc(2250000);
    float* As2   = alloc(562500);
    float* A3    = alloc(140625);
    unsigned short* Rg  = (unsigned short*)alloc(2375000);   // 4.75M bf16
    unsigned short* Cgb = (unsigned short*)alloc(2375000);   // CgbT: Npad x Kpad
    float* xn    = alloc(15000);
    float* h0    = alloc(192000);
    float* h1    = alloc(96000);
    float* h2    = alloc(48000);
    float* h3    = alloc(24000);
    float* hu0   = alloc(48000);
    float* hu1   = alloc(96000);
    float* hu2   = alloc(192000);
    float* cbuf  = alloc(384000);
    float* Y     = alloc(192000);
    float* tmp   = alloc(192000);
    float* score = alloc(3000);
    float* degw  = alloc(3000);
    float* dself = alloc(3000);
    float* dinvE = alloc(3000);  float* selfwE = alloc(3000);
    float* dinv1 = alloc(1500);  float* selfw1 = alloc(1500);
    float* dinv2 = alloc(750);   float* selfw2 = alloc(750);
    float* dinv3 = alloc(375);   float* selfw3 = alloc(375);
    float* dinvF = alloc(3000);  float* selfwF = alloc(3000);
    int* perm1 = (int*)alloc(1500);
    int* perm2 = (int*)alloc(750);
    int* perm3 = (int*)alloc(375);
    float* Y3  = alloc(9000);
    (void)ws_size; (void)in_sizes; (void)n_in; (void)out_size;

    // 1) BatchNorm
    k_bn<<<F_INF, 256, 0, stream>>>(x, bng, bnb, xn, N_NODES);

    // 2) A0 dense build + edge-based normalization for A0
    hipMemsetAsync(As0, 0, 9000000 * sizeof(float), stream);
    k_adj<<<cdiv(NE, 256), 256, 0, stream>>>(ei, As0, N_NODES);
    hipMemsetAsync(degw, 0, N_NODES * sizeof(float), stream);
    hipMemsetAsync(dself, 0, N_NODES * sizeof(float), stream);
    k_edeg<<<cdiv(NE, 256), 256, 0, stream>>>(ei, degw, dself);
    k_dinv<<<cdiv(N_NODES, 256), 256, 0, stream>>>(degw, dself, N_NODES, dinvE, selfwE);

    // 3) first GCN (A0, edge aggregation) + gelu
    gcn_edge(stream, ei, xn, F_INF, dw0, db0, dinvE, selfwE, Y, tmp, h0, true);

    // 4) down path
    struct Lvl { const float* Ain; int n, k, sz, Kpad, Npad; const float* hin;
                 const float* p; const float* Wd; const float* bd; int* perm;
                 float* Aout; float* hout; float* dinv; float* selfw; };
    Lvl lv[3] = {
        { As0, 3000, 1500, 4096, 3008, 1536, h0, p1, dw1, db1, perm1, As1, h1, dinv1, selfw1 },
        { As1, 1500,  750, 2048, 1504,  768, h1, p2, dw2, db2, perm2, As2, h2, dinv2, selfw2 },
        { As2,  750,  375, 1024,  768,  384, h2, p3, dw3, db3, perm3, A3,  h3, dinv3, selfw3 },
    };
    for (int L = 0; L < 3; ++L) {
        Lvl& v = lv[L];
        k_score_topk<<<1, 1024, 0, stream>>>(v.hin, v.p, v.n, v.k, v.sz, score, v.perm);
        k_poolx<<<cdiv(v.k * HF, 256), 256, 0, stream>>>(v.hin, score, v.perm, v.k, cbuf);
        k_gather_rg<<<cdiv(v.k * (v.Kpad >> 1), 256), 256, 0, stream>>>(
            v.Ain, v.perm, v.n, v.k, v.Kpad, Rg);
        k_gather_ct<<<dim3(v.Npad / 32, v.Kpad / 32), 256, 0, stream>>>(
            v.Ain, v.perm, v.n, v.k, v.Kpad, Cgb);
        hipMemsetAsync(degw, 0, v.k * sizeof(float), stream);
        k_pgemm_mfma<<<dim3(cdiv(v.k, 64), v.Npad / 64), 256, 0, stream>>>(
            Rg, Cgb, v.Aout, v.k, v.k, v.Kpad, degw);
        k_dinv_dense<<<cdiv(v.k, 256), 256, 0, stream>>>(degw, v.Aout, v.k, v.dinv, v.selfw);
        gcn_dense(stream, v.Aout, v.k, cbuf, HF, v.Wd, v.bd, v.dinv, v.selfw, Y, v.hout, true);
    }

    // 5) up path
    struct Up { const float* A; int n, k; const int* perm; const float* res;
                const float* hprev; const float* Wu; const float* bu; float* out;
                const float* dinv; const float* selfw; bool g; bool edge; };
    Up up[3] = {
        { As2,  750,  375, perm3, h2, h3,  uw1, ub1, hu0, dinv2, selfw2, true,  false },
        { As1, 1500,  750, perm2, h1, hu0, uw2, ub2, hu1, dinv1, selfw1, true,  false },
        { As0, 3000, 1500, perm1, h0, hu1, uw3, ub3, hu2, dinvE, selfwE, false, true  },
    };
    for (int L = 0; L < 3; ++L) {
        Up& v = up[L];
        k_concat<<<cdiv(v.n * HF, 256), 256, 0, stream>>>(v.res, cbuf, v.n);
        k_upscat<<<cdiv(v.k * HF, 256), 256, 0, stream>>>(v.hprev, v.perm, cbuf, v.k);
        if (v.edge) {
            gcn_edge(stream, ei, cbuf, 2 * HF, v.Wu, v.bu, v.dinv, v.selfw, Y, tmp, v.out, v.g);
        } else {
            gcn_dense(stream, v.A, v.n, cbuf, 2 * HF, v.Wu, v.bu, v.dinv, v.selfw, Y, v.out, v.g);
        }
    }

    // 6) final GCN with edge_attr weights (fout=3)
    hipMemsetAsync(degw, 0, N_NODES * sizeof(float), stream);
    hipMemsetAsync(dself, 0, N_NODES * sizeof(float), stream);
    k_fdeg<<<cdiv(NE, 256), 256, 0, stream>>>(ei, ea, degw, dself);
    k_dinv<<<cdiv(N_NODES, 256), 256, 0, stream>>>(degw, dself, N_NODES, dinvF, selfwF);
    k_xw<<<cdiv(N_NODES * 3, 256), 256, 0, stream>>>(hu2, fw, dinvF, N_NODES, HF, 3, Y3);
    k_finit<<<cdiv(N_NODES * 3, 256), 256, 0, stream>>>(fb, selfwF, Y3, outp, N_NODES);
    k_fedge<<<cdiv(NE, 256), 256, 0, stream>>>(ei, ea, dinvF, Y3, outp);
}

// Round 6
// 796.040 us; speedup vs baseline: 1.2955x; 1.2955x over previous
//
#include <hip/hip_runtime.h>
#include <math.h>

#define N_NODES 3000
#define F_INF 5
#define HF 64
#define NE 30000
#define SELSZ 3072   // max nodes, padded for select scan

typedef short bf16x8 __attribute__((ext_vector_type(8)));
typedef float f32x4 __attribute__((ext_vector_type(4)));

// ---------------- device helpers ----------------
static __device__ __forceinline__ float gelu_f(float v) {
    return 0.5f * v * (1.0f + erff(v * 0.70710678118654752f));
}
static __device__ __forceinline__ unsigned short f2bf(float f) {
    union { float f; unsigned u; } v; v.f = f;
    return (unsigned short)(v.u >> 16);   // truncation: exact for small integers
}

// ---------------- BatchNorm1d (training stats, biased var) ----------------
__global__ void k_bn(const float* __restrict__ x, const float* __restrict__ g,
                     const float* __restrict__ b, float* __restrict__ xn, int n) {
    int f = blockIdx.x;
    int tid = threadIdx.x;
    __shared__ float red[256];
    float s = 0.f;
    for (int v = tid; v < n; v += 256) s += x[v * F_INF + f];
    red[tid] = s; __syncthreads();
    for (int o = 128; o > 0; o >>= 1) { if (tid < o) red[tid] += red[tid + o]; __syncthreads(); }
    float mu = red[0] / n;
    __syncthreads();
    float sq = 0.f;
    for (int v = tid; v < n; v += 256) { float d = x[v * F_INF + f] - mu; sq += d * d; }
    red[tid] = sq; __syncthreads();
    for (int o = 128; o > 0; o >>= 1) { if (tid < o) red[tid] += red[tid + o]; __syncthreads(); }
    float rs = 1.0f / sqrtf(red[0] / n + 1e-5f);
    float gg = g[f], bb = b[f];
    for (int v = tid; v < n; v += 256)
        xn[v * F_INF + f] = (x[v * F_INF + f] - mu) * rs * gg + bb;
}

// ---------------- dense adjacency build (unit weights) ----------------
__global__ void k_adj(const int* __restrict__ ei, float* __restrict__ A, int n) {
    int e = blockIdx.x * blockDim.x + threadIdx.x;
    if (e >= NE) return;
    atomicAdd(&A[(size_t)ei[e] * n + ei[NE + e]], 1.0f);
}

// ---------------- degrees ----------------
__global__ void k_edeg(const int* __restrict__ ei, float* __restrict__ degw,
                       float* __restrict__ dself) {
    int e = blockIdx.x * blockDim.x + threadIdx.x;
    if (e >= NE) return;
    int s = ei[e], d = ei[NE + e];
    atomicAdd(&degw[d], 1.0f);
    if (s == d) atomicAdd(&dself[d], 1.0f);
}

__global__ void k_fdeg(const int* __restrict__ ei, const float* __restrict__ ea,
                       float* __restrict__ degw, float* __restrict__ dself) {
    int e = blockIdx.x * blockDim.x + threadIdx.x;
    if (e >= NE) return;
    int s = ei[e], d = ei[NE + e];
    float w = ea[e];
    atomicAdd(&degw[d], w);
    if (s == d) atomicAdd(&dself[d], w);
}

// dinv from edge-accumulated degw/dself
__global__ void k_dinv(const float* __restrict__ degw, const float* __restrict__ dself,
                       int n, float* __restrict__ dinv, float* __restrict__ selfw) {
    int j = blockIdx.x * 256 + threadIdx.x;
    if (j >= n) return;
    float dl = (dself[j] == 0.f) ? 1.f : 0.f;
    float deg = degw[j] + dl;
    float di = (deg > 0.f) ? (1.0f / sqrtf(deg)) : 0.f;
    dinv[j] = di;
    selfw[j] = dl * di;
}

// dinv for dense A (degw pre-accumulated by pgemm epilogue): reads diagonal directly
__global__ void k_dinv_dense(const float* __restrict__ degw, const float* __restrict__ A,
                             int n, float* __restrict__ dinv, float* __restrict__ selfw) {
    int j = blockIdx.x * 256 + threadIdx.x;
    if (j >= n) return;
    float dl = (A[(size_t)j * n + j] == 0.f) ? 1.f : 0.f;
    float deg = degw[j] + dl;
    float di = (deg > 0.f) ? (1.0f / sqrtf(deg)) : 0.f;
    dinv[j] = di;
    selfw[j] = dl * di;
}

// ---------------- Y = dinv[v] * (X @ W) ----------------
__global__ void k_xw(const float* __restrict__ X, const float* __restrict__ Wm,
                     const float* __restrict__ dinv, int n, int fin, int fout,
                     float* __restrict__ Y) {
    int t = blockIdx.x * blockDim.x + threadIdx.x;
    if (t >= n * fout) return;
    int v = t / fout, fo = t % fout;
    float s = 0.f;
    for (int fi = 0; fi < fin; ++fi) s += X[v * fin + fi] * Wm[fi * fout + fo];
    Y[t] = dinv[v] * s;
}

// ---------------- edge aggregation (A0-based GCNs, fout=64) ----------------
__global__ void k_eagg(const int* __restrict__ ei, const float* __restrict__ Y,
                       float* __restrict__ tmp) {
    int t = blockIdx.x * blockDim.x + threadIdx.x;
    if (t >= NE * HF) return;
    int e = t >> 6, f = t & 63;
    atomicAdd(&tmp[(size_t)ei[NE + e] * HF + f], Y[(size_t)ei[e] * HF + f]);
}

// epilogue shared by edge- and dense-aggregation paths
__global__ void k_gcn_fin(const float* __restrict__ tmp, const float* __restrict__ Y,
                          const float* __restrict__ dinv, const float* __restrict__ selfw,
                          const float* __restrict__ bias, float* __restrict__ out,
                          int n, int dogelu) {
    int t = blockIdx.x * blockDim.x + threadIdx.x;
    if (t >= n * HF) return;
    int v = t >> 6, f = t & 63;
    float val = dinv[v] * tmp[t] + selfw[v] * Y[t] + bias[f];
    if (dogelu) val = gelu_f(val);
    out[t] = val;
}

// ---------------- dense aggregation, split-K: accum += A[k0:k1]^T @ Y[k0:k1] ----------
__global__ void k_aggS(const float* __restrict__ A, const float* __restrict__ Y,
                       float* __restrict__ accum, int n, int kchunk) {
    __shared__ float As[16][17];
    __shared__ float Bs[16][68];
    int i0 = blockIdx.x * 16;
    int kbeg = blockIdx.y * kchunk;
    int kend = min(n, kbeg + kchunk);
    int tid = threadIdx.x;
    int tr = tid >> 4, tc = tid & 15;
    float acc[4] = {};
    for (int k0 = kbeg; k0 < kend; k0 += 16) {
        {   // stage A: 16k x 16i
            int kk = tid >> 4, ii = tid & 15;
            int gk = k0 + kk, gi = i0 + ii;
            As[kk][ii] = (gk < kend && gi < n) ? A[(size_t)gk * n + gi] : 0.f;
        }
        {   // stage Y: 16k x 64f (float4)
            int kk = tid >> 4, f4 = (tid & 15) * 4;
            int gk = k0 + kk;
            if (gk < kend) {
                float4 v = *(const float4*)&Y[(size_t)gk * HF + f4];
                *(float4*)&Bs[kk][f4] = v;
            } else {
                float4 z = {0.f, 0.f, 0.f, 0.f};
                *(float4*)&Bs[kk][f4] = z;
            }
        }
        __syncthreads();
#pragma unroll
        for (int kk = 0; kk < 16; ++kk) {
            float a = As[kk][tr];
#pragma unroll
            for (int w = 0; w < 4; ++w) acc[w] += a * Bs[kk][tc * 4 + w];
        }
        __syncthreads();
    }
    int i = i0 + tr;
    if (i < n) {
#pragma unroll
        for (int w = 0; w < 4; ++w)
            if (acc[w] != 0.f) atomicAdd(&accum[(size_t)i * HF + tc * 4 + w], acc[w]);
    }
}

// ---------------- TopK select: score + exact radix-select + prefix-scan perm ----------
// Selected SET identical to jax.lax.top_k (incl. lowest-index tie-break); perm emitted in
// ascending-index order (valid: entire network is permutation-equivariant over the set).
__global__ __launch_bounds__(1024) void k_select(
    const float* __restrict__ h, const float* __restrict__ p, int n, int k,
    float* __restrict__ score, int* __restrict__ perm) {
    __shared__ unsigned key[SELSZ];
    __shared__ unsigned long long ps[SELSZ];
    __shared__ unsigned hist[256];
    __shared__ float pp[HF];
    __shared__ unsigned sPrefix;
    __shared__ int sRemain;
    int tid = threadIdx.x;
    if (tid < HF) pp[tid] = p[tid];
    if (tid == 0) { sPrefix = 0; sRemain = k; }
    __syncthreads();
    float pn = 0.f;
#pragma unroll
    for (int f = 0; f < HF; ++f) pn += pp[f] * pp[f];
    float rnorm = 1.0f / sqrtf(pn);
    for (int v = tid; v < SELSZ; v += 1024) {
        unsigned u = 0;
        if (v < n) {
            float dot = 0.f;
            const float4* hr = (const float4*)&h[(size_t)v * HF];
#pragma unroll
            for (int q = 0; q < 16; ++q) {
                float4 hv = hr[q];
                dot += hv.x * pp[q * 4] + hv.y * pp[q * 4 + 1] +
                       hv.z * pp[q * 4 + 2] + hv.w * pp[q * 4 + 3];
            }
            float sc = tanhf(dot * rnorm);
            score[v] = sc;
            unsigned b = __float_as_uint(sc);
            u = (b & 0x80000000u) ? ~b : (b | 0x80000000u);  // monotone map
        }
        key[v] = u;
    }
    __syncthreads();
    // 4-pass radix select (MSB first) for the k-th largest key
    for (int pass = 0; pass < 4; ++pass) {
        int shift = 24 - 8 * pass;
        if (tid < 256) hist[tid] = 0;
        __syncthreads();
        unsigned maskHi = (pass == 0) ? 0u : (0xFFFFFFFFu << (32 - 8 * pass));
        unsigned pfx = sPrefix;
        for (int v = tid; v < n; v += 1024) {
            unsigned u = key[v];
            if ((u & maskHi) == (pfx & maskHi))
                atomicAdd(&hist[(u >> shift) & 255u], 1u);
        }
        __syncthreads();
        if (tid == 0) {
            unsigned cum = 0;
            for (int b = 255; b >= 0; --b) {
                unsigned c = hist[b];
                if (cum + c >= (unsigned)sRemain) {
                    sPrefix |= ((unsigned)b) << shift;
                    sRemain -= (int)cum;
                    break;
                }
                cum += c;
            }
        }
        __syncthreads();
    }
    unsigned T = sPrefix;
    int take = sRemain;     // # of keys == T to keep (lowest indices)
    // pair prefix scan: hi32 = count(key>T), lo32 = count(key==T)
    for (int v = tid; v < SELSZ; v += 1024) {
        unsigned long long gt = (v < n && key[v] > T) ? 1ull : 0ull;
        unsigned long long eq = (v < n && key[v] == T) ? 1ull : 0ull;
        ps[v] = (gt << 32) | eq;
    }
    __syncthreads();
    for (int off = 1; off < SELSZ; off <<= 1) {
        unsigned long long t0 = 0, t1 = 0, t2 = 0;
        int v0 = tid, v1 = tid + 1024, v2 = tid + 2048;
        if (v0 >= off) t0 = ps[v0 - off];
        if (v1 >= off) t1 = ps[v1 - off];
        if (v2 >= off) t2 = ps[v2 - off];
        __syncthreads();
        ps[v0] += t0; ps[v1] += t1; ps[v2] += t2;
        __syncthreads();
    }
    for (int v = tid; v < n; v += 1024) {
        unsigned u = key[v];
        bool gt = u > T, eq = u == T;
        unsigned long long pv = ps[v];
        int p1 = (int)(pv >> 32) - (gt ? 1 : 0);          // exclusive gt count
        int p2 = (int)(pv & 0xFFFFFFFFull) - (eq ? 1 : 0); // exclusive eq count
        bool sel = gt || (eq && p2 < take);
        if (sel) perm[p1 + min(p2, take)] = v;
    }
}

__global__ void k_poolx(const float* __restrict__ h, const float* __restrict__ score,
                        const int* __restrict__ perm, int k, float* __restrict__ hp) {
    int t = blockIdx.x * blockDim.x + threadIdx.x;
    if (t >= k * HF) return;
    int i = t / HF, f = t % HF;
    int pi = perm[i];
    hp[t] = h[pi * HF + f] * score[pi];
}

// ---------------- bf16 gathers for the augment GEMM ----------------
// Rg[i*Kpad+m] = A[perm_i * nfull + m]
__global__ void k_gather_rg(const float* __restrict__ A, const int* __restrict__ perm,
                            int nfull, int M, int Kpad, unsigned short* __restrict__ Rg) {
    int t = blockIdx.x * blockDim.x + threadIdx.x;
    int kh = Kpad >> 1;
    if (t >= M * kh) return;
    int i = t / kh, m2 = (t - i * kh) * 2;
    const float* row = A + (size_t)perm[i] * nfull;
    float v0 = 0.f, v1 = 0.f;
    if (m2 + 1 < nfull) { float2 vv = *(const float2*)&row[m2]; v0 = vv.x; v1 = vv.y; }
    else if (m2 < nfull) { v0 = row[m2]; }
    unsigned pk = (unsigned)f2bf(v0) | ((unsigned)f2bf(v1) << 16);
    *(unsigned*)&Rg[(size_t)i * Kpad + m2] = pk;
}

// CgbT[j*Kpad+m] = A[m * nfull + perm_j] + 2*(m==perm_j)
__global__ __launch_bounds__(256) void k_gather_ct(
    const float* __restrict__ A, const int* __restrict__ perm,
    int nfull, int Nc, int Kpad, unsigned short* __restrict__ CgbT) {
    __shared__ float Ts[32][33];
    int j0 = blockIdx.x * 32, m0 = blockIdx.y * 32;
    int t = threadIdx.x;
    {   // read phase: m-major lanes, gathered columns of A
        int ml = t >> 3, jl4 = (t & 7) * 4;
        int m = m0 + ml;
#pragma unroll
        for (int e = 0; e < 4; ++e) {
            int j = j0 + jl4 + e;
            float v = 0.f;
            if (m < nfull && j < Nc) {
                int pj = perm[j];
                v = A[(size_t)m * nfull + pj];
                if (m == pj) v += 2.f;
            }
            Ts[jl4 + e][ml] = v;
        }
    }
    __syncthreads();
    {   // write phase: j-major lanes, coalesced ushort4 stores
        int jl = t >> 3, mq = (t & 7) * 4;
        unsigned lo = (unsigned)f2bf(Ts[jl][mq])     | ((unsigned)f2bf(Ts[jl][mq + 1]) << 16);
        unsigned hi = (unsigned)f2bf(Ts[jl][mq + 2]) | ((unsigned)f2bf(Ts[jl][mq + 3]) << 16);
        uint2 w; w.x = lo; w.y = hi;
        *(uint2*)&CgbT[(size_t)(j0 + jl) * Kpad + m0 + mq] = w;
    }
}

// ---------------- MFMA bf16 GEMM: C[i][j] = sum_m Rg[i][m]*CgbT[j][m]; diag=0 ----------------
__global__ __launch_bounds__(256) void k_pgemm_mfma(
    const unsigned short* __restrict__ Rg,    // M x Kpad (row-major)
    const unsigned short* __restrict__ CgbT,  // Npad x Kpad (row-major = B^T)
    float* __restrict__ C, int M, int Nc, int Kpad,
    float* __restrict__ degw) {
    __shared__ __align__(16) unsigned short As[64][40];
    __shared__ __align__(16) unsigned short Bs[64][40];
    int i0 = blockIdx.x * 64, j0 = blockIdx.y * 64;
    int tid = threadIdx.x;
    int lane = tid & 63, wid = tid >> 6;
    int wm = wid >> 1, wn = wid & 1;
    f32x4 acc[2][2] = {};
    int r = lane & 15, kq = lane >> 4;
    int srow = tid >> 2, scq = (tid & 3) * 8;
    for (int k0 = 0; k0 < Kpad; k0 += 32) {
        int gi = i0 + srow;
        bf16x8 av = {0, 0, 0, 0, 0, 0, 0, 0};
        if (gi < M) av = *(const bf16x8*)&Rg[(size_t)gi * Kpad + k0 + scq];
        bf16x8 bv = *(const bf16x8*)&CgbT[(size_t)(j0 + srow) * Kpad + k0 + scq];
        *(bf16x8*)&As[srow][scq] = av;
        *(bf16x8*)&Bs[srow][scq] = bv;
        __syncthreads();
        bf16x8 a0 = *(const bf16x8*)&As[wm * 32 + r][kq * 8];
        bf16x8 a1 = *(const bf16x8*)&As[wm * 32 + 16 + r][kq * 8];
        bf16x8 b0 = *(const bf16x8*)&Bs[wn * 32 + r][kq * 8];
        bf16x8 b1 = *(const bf16x8*)&Bs[wn * 32 + 16 + r][kq * 8];
        acc[0][0] = __builtin_amdgcn_mfma_f32_16x16x32_bf16(a0, b0, acc[0][0], 0, 0, 0);
        acc[0][1] = __builtin_amdgcn_mfma_f32_16x16x32_bf16(a0, b1, acc[0][1], 0, 0, 0);
        acc[1][0] = __builtin_amdgcn_mfma_f32_16x16x32_bf16(a1, b0, acc[1][0], 0, 0, 0);
        acc[1][1] = __builtin_amdgcn_mfma_f32_16x16x32_bf16(a1, b1, acc[1][1], 0, 0, 0);
        __syncthreads();
    }
#pragma unroll
    for (int nj = 0; nj < 2; ++nj) {
        int j = j0 + wn * 32 + nj * 16 + r;
        float csum = 0.f;
#pragma unroll
        for (int mi = 0; mi < 2; ++mi)
#pragma unroll
            for (int reg = 0; reg < 4; ++reg) {
                int i = i0 + wm * 32 + mi * 16 + kq * 4 + reg;
                if (i < M && j < Nc) {
                    float v = acc[mi][nj][reg];
                    if (i == j) v = 0.f;
                    C[(size_t)i * Nc + j] = v;
                    csum += v;
                }
            }
        if (j < Nc && csum != 0.f) atomicAdd(&degw[j], csum);
    }
}

// ---------------- unpool (concat skip) ----------------
__global__ void k_concat(const float* __restrict__ res, float* __restrict__ c, int n) {
    int t = blockIdx.x * blockDim.x + threadIdx.x;
    if (t >= n * HF) return;
    int v = t / HF, f = t % HF;
    c[v * (2 * HF) + f] = res[t];
    c[v * (2 * HF) + HF + f] = 0.f;
}

__global__ void k_upscat(const float* __restrict__ h, const int* __restrict__ perm,
                         float* __restrict__ c, int k) {
    int t = blockIdx.x * blockDim.x + threadIdx.x;
    if (t >= k * HF) return;
    int i = t / HF, f = t % HF;
    c[perm[i] * (2 * HF) + HF + f] = h[t];
}

// ---------------- final edge-based GCN (fout=3) ----------------
__global__ void k_finit(const float* __restrict__ fb, const float* __restrict__ selfw,
                        const float* __restrict__ Y3, float* __restrict__ out, int n) {
    int t = blockIdx.x * blockDim.x + threadIdx.x;
    if (t >= n * 3) return;
    int j = t / 3, f = t % 3;
    out[t] = fb[f] + selfw[j] * Y3[t];
}

__global__ void k_fedge(const int* __restrict__ ei, const float* __restrict__ ea,
                        const float* __restrict__ dinv, const float* __restrict__ Y3,
                        float* __restrict__ out) {
    int e = blockIdx.x * blockDim.x + threadIdx.x;
    if (e >= NE) return;
    int s = ei[e], d = ei[NE + e];
    float c = ea[e] * dinv[d];
    atomicAdd(&out[d * 3 + 0], c * Y3[s * 3 + 0]);
    atomicAdd(&out[d * 3 + 1], c * Y3[s * 3 + 1]);
    atomicAdd(&out[d * 3 + 2], c * Y3[s * 3 + 2]);
}

// ================= host orchestration =================
static inline int cdiv(int a, int b) { return (a + b - 1) / b; }

static void gcn_dense(hipStream_t st, const float* A, int n, const float* X, int fin,
                      const float* Wm, const float* bias, const float* dinv,
                      const float* selfw, float* Y, float* accum, float* out, bool gelu) {
    k_xw<<<cdiv(n * HF, 256), 256, 0, st>>>(X, Wm, dinv, n, fin, HF, Y);
    hipMemsetAsync(accum, 0, (size_t)n * HF * sizeof(float), st);
    int nsplit = cdiv(n, 192);
    k_aggS<<<dim3(cdiv(n, 16), nsplit), 256, 0, st>>>(A, Y, accum, n, 192);
    k_gcn_fin<<<cdiv(n * HF, 256), 256, 0, st>>>(accum, Y, dinv, selfw, bias, out, n,
                                                 gelu ? 1 : 0);
}

static void gcn_edge(hipStream_t st, const int* ei, const float* X, int fin,
                     const float* Wm, const float* bias, const float* dinv,
                     const float* selfw, float* Y, float* tmp, float* out, bool gelu) {
    k_xw<<<cdiv(N_NODES * HF, 256), 256, 0, st>>>(X, Wm, dinv, N_NODES, fin, HF, Y);
    hipMemsetAsync(tmp, 0, N_NODES * HF * sizeof(float), st);
    k_eagg<<<cdiv(NE * HF, 256), 256, 0, st>>>(ei, Y, tmp);
    k_gcn_fin<<<cdiv(N_NODES * HF, 256), 256, 0, st>>>(tmp, Y, dinv, selfw, bias, out,
                                                       N_NODES, gelu ? 1 : 0);
}

extern "C" void kernel_launch(void* const* d_in, const int* in_sizes, int n_in,
                              void* d_out, int out_size, void* d_ws, size_t ws_size,
                              hipStream_t stream) {
    const float* x   = (const float*)d_in[0];
    const int*   ei  = (const int*)d_in[1];
    const float* ea  = (const float*)d_in[2];
    const float* bng = (const float*)d_in[3];
    const float* bnb = (const float*)d_in[4];
    const float* dw0 = (const float*)d_in[5];
    const float* db0 = (const float*)d_in[6];
    const float* dw1 = (const float*)d_in[7];
    const float* db1 = (const float*)d_in[8];
    const float* dw2 = (const float*)d_in[9];
    const float* db2 = (const float*)d_in[10];
    const float* dw3 = (const float*)d_in[11];
    const float* db3 = (const float*)d_in[12];
    const float* p1  = (const float*)d_in[13];
    const float* p2  = (const float*)d_in[14];
    const float* p3  = (const float*)d_in[15];
    const float* uw1 = (const float*)d_in[16];
    const float* ub1 = (const float*)d_in[17];
    const float* uw2 = (const float*)d_in[18];
    const float* ub2 = (const float*)d_in[19];
    const float* uw3 = (const float*)d_in[20];
    const float* ub3 = (const float*)d_in[21];
    const float* fw  = (const float*)d_in[22];
    const float* fb  = (const float*)d_in[23];
    float* outp = (float*)d_out;

    // workspace layout (floats, 16B-aligned slots)
    float* W = (float*)d_ws;
    size_t o = 0;
    auto alloc = [&](size_t cnt) { float* p = W + o; o += (cnt + 3) & ~size_t(3); return p; };
    float* As0   = alloc(9000000);
    float* As1   = alloc(2250000);
    float* As2   = alloc(562500);
    float* A3    = alloc(140625);
    unsigned short* Rg  = (unsigned short*)alloc(2375000);   // 4.75M bf16
    unsigned short* Cgb = (unsigned short*)alloc(2375000);   // CgbT: Npad x Kpad
    float* xn    = alloc(15000);
    float* h0    = alloc(192000);
    float* h1    = alloc(96000);
    float* h2    = alloc(48000);
    float* h3    = alloc(24000);
    float* hu0   = alloc(48000);
    float* hu1   = alloc(96000);
    float* hu2   = alloc(192000);
    float* cbuf  = alloc(384000);
    float* Y     = alloc(192000);
    float* tmp   = alloc(192000);
    float* score = alloc(3000);
    float* degw  = alloc(3000);
    float* dself = alloc(3000);
    float* dinvE = alloc(3000);  float* selfwE = alloc(3000);
    float* dinv1 = alloc(1500);  float* selfw1 = alloc(1500);
    float* dinv2 = alloc(750);   float* selfw2 = alloc(750);
    float* dinv3 = alloc(375);   float* selfw3 = alloc(375);
    float* dinvF = alloc(3000);  float* selfwF = alloc(3000);
    int* perm1 = (int*)alloc(1500);
    int* perm2 = (int*)alloc(750);
    int* perm3 = (int*)alloc(375);
    float* Y3  = alloc(9000);
    (void)ws_size; (void)in_sizes; (void)n_in; (void)out_size;

    // 1) BatchNorm
    k_bn<<<F_INF, 256, 0, stream>>>(x, bng, bnb, xn, N_NODES);

    // 2) A0 dense build + edge-based normalization for A0
    hipMemsetAsync(As0, 0, 9000000 * sizeof(float), stream);
    k_adj<<<cdiv(NE, 256), 256, 0, stream>>>(ei, As0, N_NODES);
    hipMemsetAsync(degw, 0, N_NODES * sizeof(float), stream);
    hipMemsetAsync(dself, 0, N_NODES * sizeof(float), stream);
    k_edeg<<<cdiv(NE, 256), 256, 0, stream>>>(ei, degw, dself);
    k_dinv<<<cdiv(N_NODES, 256), 256, 0, stream>>>(degw, dself, N_NODES, dinvE, selfwE);

    // 3) first GCN (A0, edge aggregation) + gelu
    gcn_edge(stream, ei, xn, F_INF, dw0, db0, dinvE, selfwE, Y, tmp, h0, true);

    // 4) down path
    struct Lvl { const float* Ain; int n, k, Kpad, Npad; const float* hin;
                 const float* p; const float* Wd; const float* bd; int* perm;
                 float* Aout; float* hout; float* dinv; float* selfw; };
    Lvl lv[3] = {
        { As0, 3000, 1500, 3008, 1536, h0, p1, dw1, db1, perm1, As1, h1, dinv1, selfw1 },
        { As1, 1500,  750, 1504,  768, h1, p2, dw2, db2, perm2, As2, h2, dinv2, selfw2 },
        { As2,  750,  375,  768,  384, h2, p3, dw3, db3, perm3, A3,  h3, dinv3, selfw3 },
    };
    for (int L = 0; L < 3; ++L) {
        Lvl& v = lv[L];
        k_select<<<1, 1024, 0, stream>>>(v.hin, v.p, v.n, v.k, score, v.perm);
        k_poolx<<<cdiv(v.k * HF, 256), 256, 0, stream>>>(v.hin, score, v.perm, v.k, cbuf);
        k_gather_rg<<<cdiv(v.k * (v.Kpad >> 1), 256), 256, 0, stream>>>(
            v.Ain, v.perm, v.n, v.k, v.Kpad, Rg);
        k_gather_ct<<<dim3(v.Npad / 32, v.Kpad / 32), 256, 0, stream>>>(
            v.Ain, v.perm, v.n, v.k, v.Kpad, Cgb);
        hipMemsetAsync(degw, 0, v.k * sizeof(float), stream);
        k_pgemm_mfma<<<dim3(cdiv(v.k, 64), v.Npad / 64), 256, 0, stream>>>(
            Rg, Cgb, v.Aout, v.k, v.k, v.Kpad, degw);
        k_dinv_dense<<<cdiv(v.k, 256), 256, 0, stream>>>(degw, v.Aout, v.k, v.dinv, v.selfw);
        gcn_dense(stream, v.Aout, v.k, cbuf, HF, v.Wd, v.bd, v.dinv, v.selfw, Y, tmp,
                  v.hout, true);
    }

    // 5) up path
    struct Up { const float* A; int n, k; const int* perm; const float* res;
                const float* hprev; const float* Wu; const float* bu; float* out;
                const float* dinv; const float* selfw; bool g; bool edge; };
    Up up[3] = {
        { As2,  750,  375, perm3, h2, h3,  uw1, ub1, hu0, dinv2, selfw2, true,  false },
        { As1, 1500,  750, perm2, h1, hu0, uw2, ub2, hu1, dinv1, selfw1, true,  false },
        { As0, 3000, 1500, perm1, h0, hu1, uw3, ub3, hu2, dinvE, selfwE, false, true  },
    };
    for (int L = 0; L < 3; ++L) {
        Up& v = up[L];
        k_concat<<<cdiv(v.n * HF, 256), 256, 0, stream>>>(v.res, cbuf, v.n);
        k_upscat<<<cdiv(v.k * HF, 256), 256, 0, stream>>>(v.hprev, v.perm, cbuf, v.k);
        if (v.edge) {
            gcn_edge(stream, ei, cbuf, 2 * HF, v.Wu, v.bu, v.dinv, v.selfw, Y, tmp, v.out, v.g);
        } else {
            gcn_dense(stream, v.A, v.n, cbuf, 2 * HF, v.Wu, v.bu, v.dinv, v.selfw, Y, tmp,
                      v.out, v.g);
        }
    }

    // 6) final GCN with edge_attr weights (fout=3)
    hipMemsetAsync(degw, 0, N_NODES * sizeof(float), stream);
    hipMemsetAsync(dself, 0, N_NODES * sizeof(float), stream);
    k_fdeg<<<cdiv(NE, 256), 256, 0, stream>>>(ei, ea, degw, dself);
    k_dinv<<<cdiv(N_NODES, 256), 256, 0, stream>>>(degw, dself, N_NODES, dinvF, selfwF);
    k_xw<<<cdiv(N_NODES * 3, 256), 256, 0, stream>>>(hu2, fw, dinvF, N_NODES, HF, 3, Y3);
    k_finit<<<cdiv(N_NODES * 3, 256), 256, 0, stream>>>(fb, selfwF, Y3, outp, N_NODES);
    k_fedge<<<cdiv(NE, 256), 256, 0, stream>>>(ei, ea, dinvF, Y3, outp);
}

// Round 10
// 703.022 us; speedup vs baseline: 1.4670x; 1.1323x over previous
//
#include <hip/hip_runtime.h>
#include <math.h>

#define N_NODES 3000
#define F_INF 5
#define HF 64
#define NE 30000
#define SELSZ 3072   // max nodes, padded for select scan

typedef short bf16x8 __attribute__((ext_vector_type(8)));
typedef float f32x4 __attribute__((ext_vector_type(4)));

// ---------------- device helpers ----------------
static __device__ __forceinline__ float gelu_f(float v) {
    return 0.5f * v * (1.0f + erff(v * 0.70710678118654752f));
}
static __device__ __forceinline__ unsigned short f2bf(float f) {
    union { float f; unsigned u; } v; v.f = f;
    return (unsigned short)(v.u >> 16);   // truncation: exact for small integers
}

// ---------------- BatchNorm1d (training stats, biased var) ----------------
__global__ void k_bn(const float* __restrict__ x, const float* __restrict__ g,
                     const float* __restrict__ b, float* __restrict__ xn, int n) {
    int f = blockIdx.x;
    int tid = threadIdx.x;
    __shared__ float red[256];
    float s = 0.f;
    for (int v = tid; v < n; v += 256) s += x[v * F_INF + f];
    red[tid] = s; __syncthreads();
    for (int o = 128; o > 0; o >>= 1) { if (tid < o) red[tid] += red[tid + o]; __syncthreads(); }
    float mu = red[0] / n;
    __syncthreads();
    float sq = 0.f;
    for (int v = tid; v < n; v += 256) { float d = x[v * F_INF + f] - mu; sq += d * d; }
    red[tid] = sq; __syncthreads();
    for (int o = 128; o > 0; o >>= 1) { if (tid < o) red[tid] += red[tid + o]; __syncthreads(); }
    float rs = 1.0f / sqrtf(red[0] / n + 1e-5f);
    float gg = g[f], bb = b[f];
    for (int v = tid; v < n; v += 256)
        xn[v * F_INF + f] = (x[v * F_INF + f] - mu) * rs * gg + bb;
}

// ---------------- dense adjacency build (unit weights) ----------------
__global__ void k_adj(const int* __restrict__ ei, float* __restrict__ A, int n) {
    int e = blockIdx.x * blockDim.x + threadIdx.x;
    if (e >= NE) return;
    atomicAdd(&A[(size_t)ei[e] * n + ei[NE + e]], 1.0f);
}

// ---------------- degrees ----------------
__global__ void k_edeg(const int* __restrict__ ei, float* __restrict__ degw,
                       float* __restrict__ dself) {
    int e = blockIdx.x * blockDim.x + threadIdx.x;
    if (e >= NE) return;
    int s = ei[e], d = ei[NE + e];
    atomicAdd(&degw[d], 1.0f);
    if (s == d) atomicAdd(&dself[d], 1.0f);
}

__global__ void k_fdeg(const int* __restrict__ ei, const float* __restrict__ ea,
                       float* __restrict__ degw, float* __restrict__ dself) {
    int e = blockIdx.x * blockDim.x + threadIdx.x;
    if (e >= NE) return;
    int s = ei[e], d = ei[NE + e];
    float w = ea[e];
    atomicAdd(&degw[d], w);
    if (s == d) atomicAdd(&dself[d], w);
}

// dinv from edge-accumulated degw/dself
__global__ void k_dinv(const float* __restrict__ degw, const float* __restrict__ dself,
                       int n, float* __restrict__ dinv, float* __restrict__ selfw) {
    int j = blockIdx.x * 256 + threadIdx.x;
    if (j >= n) return;
    float dl = (dself[j] == 0.f) ? 1.f : 0.f;
    float deg = degw[j] + dl;
    float di = (deg > 0.f) ? (1.0f / sqrtf(deg)) : 0.f;
    dinv[j] = di;
    selfw[j] = dl * di;
}

// dinv for dense A (degw pre-accumulated by pgemm epilogue): reads diagonal directly
__global__ void k_dinv_dense(const float* __restrict__ degw, const float* __restrict__ A,
                             int n, float* __restrict__ dinv, float* __restrict__ selfw) {
    int j = blockIdx.x * 256 + threadIdx.x;
    if (j >= n) return;
    float dl = (A[(size_t)j * n + j] == 0.f) ? 1.f : 0.f;
    float deg = degw[j] + dl;
    float di = (deg > 0.f) ? (1.0f / sqrtf(deg)) : 0.f;
    dinv[j] = di;
    selfw[j] = dl * di;
}

// ---------------- Y = dinv[v] * (X @ W) ----------------
__global__ void k_xw(const float* __restrict__ X, const float* __restrict__ Wm,
                     const float* __restrict__ dinv, int n, int fin, int fout,
                     float* __restrict__ Y) {
    int t = blockIdx.x * blockDim.x + threadIdx.x;
    if (t >= n * fout) return;
    int v = t / fout, fo = t % fout;
    float s = 0.f;
    for (int fi = 0; fi < fin; ++fi) s += X[v * fin + fi] * Wm[fi * fout + fo];
    Y[t] = dinv[v] * s;
}

// ---------------- edge aggregation (A0-based GCNs, fout=64) ----------------
__global__ void k_eagg(const int* __restrict__ ei, const float* __restrict__ Y,
                       float* __restrict__ tmp) {
    int t = blockIdx.x * blockDim.x + threadIdx.x;
    if (t >= NE * HF) return;
    int e = t >> 6, f = t & 63;
    atomicAdd(&tmp[(size_t)ei[NE + e] * HF + f], Y[(size_t)ei[e] * HF + f]);
}

// epilogue shared by edge- and dense-aggregation paths
__global__ void k_gcn_fin(const float* __restrict__ tmp, const float* __restrict__ Y,
                          const float* __restrict__ dinv, const float* __restrict__ selfw,
                          const float* __restrict__ bias, float* __restrict__ out,
                          int n, int dogelu) {
    int t = blockIdx.x * blockDim.x + threadIdx.x;
    if (t >= n * HF) return;
    int v = t >> 6, f = t & 63;
    float val = dinv[v] * tmp[t] + selfw[v] * Y[t] + bias[f];
    if (dogelu) val = gelu_f(val);
    out[t] = val;
}

// ---------------- dense aggregation, split-K: accum += A[k0:k1]^T @ Y[k0:k1] ----------
__global__ void k_aggS(const float* __restrict__ A, const float* __restrict__ Y,
                       float* __restrict__ accum, int n, int kchunk) {
    __shared__ float As[16][17];
    __shared__ float Bs[16][68];
    int i0 = blockIdx.x * 16;
    int kbeg = blockIdx.y * kchunk;
    int kend = min(n, kbeg + kchunk);
    int tid = threadIdx.x;
    int tr = tid >> 4, tc = tid & 15;
    float acc[4] = {};
    for (int k0 = kbeg; k0 < kend; k0 += 16) {
        {   // stage A: 16k x 16i
            int kk = tid >> 4, ii = tid & 15;
            int gk = k0 + kk, gi = i0 + ii;
            As[kk][ii] = (gk < kend && gi < n) ? A[(size_t)gk * n + gi] : 0.f;
        }
        {   // stage Y: 16k x 64f (float4)
            int kk = tid >> 4, f4 = (tid & 15) * 4;
            int gk = k0 + kk;
            if (gk < kend) {
                float4 v = *(const float4*)&Y[(size_t)gk * HF + f4];
                *(float4*)&Bs[kk][f4] = v;
            } else {
                float4 z = {0.f, 0.f, 0.f, 0.f};
                *(float4*)&Bs[kk][f4] = z;
            }
        }
        __syncthreads();
#pragma unroll
        for (int kk = 0; kk < 16; ++kk) {
            float a = As[kk][tr];
#pragma unroll
            for (int w = 0; w < 4; ++w) acc[w] += a * Bs[kk][tc * 4 + w];
        }
        __syncthreads();
    }
    int i = i0 + tr;
    if (i < n) {
#pragma unroll
        for (int w = 0; w < 4; ++w)
            if (acc[w] != 0.f) atomicAdd(&accum[(size_t)i * HF + tc * 4 + w], acc[w]);
    }
}

// ---------------- TopK select: score + exact radix-select + prefix-scan perm ----------
// Selected SET identical to jax.lax.top_k (incl. lowest-index tie-break); perm emitted in
// ascending-index order (valid: network is permutation-equivariant over the set).
// Bin-crossing search is PARALLEL (suffix-inclusive scan over 256 bins) — the previous
// serial tid==0 loop was ~55us of dependent LDS latency.
__global__ __launch_bounds__(1024) void k_select(
    const float* __restrict__ h, const float* __restrict__ p, int n, int k,
    float* __restrict__ score, int* __restrict__ perm) {
    __shared__ unsigned key[SELSZ];
    __shared__ unsigned long long ps[SELSZ];
    __shared__ unsigned hist[256];
    __shared__ float pp[HF];
    __shared__ unsigned sPrefix;
    __shared__ int sRemain;
    int tid = threadIdx.x;
    if (tid < HF) pp[tid] = p[tid];
    if (tid == 0) { sPrefix = 0; sRemain = k; }
    __syncthreads();
    float pn = 0.f;
#pragma unroll
    for (int f = 0; f < HF; ++f) pn += pp[f] * pp[f];
    float rnorm = 1.0f / sqrtf(pn);
    for (int v = tid; v < SELSZ; v += 1024) {
        unsigned u = 0;
        if (v < n) {
            float dot = 0.f;
            const float4* hr = (const float4*)&h[(size_t)v * HF];
#pragma unroll
            for (int q = 0; q < 16; ++q) {
                float4 hv = hr[q];
                dot += hv.x * pp[q * 4] + hv.y * pp[q * 4 + 1] +
                       hv.z * pp[q * 4 + 2] + hv.w * pp[q * 4 + 3];
            }
            float sc = tanhf(dot * rnorm);
            score[v] = sc;
            unsigned b = __float_as_uint(sc);
            u = (b & 0x80000000u) ? ~b : (b | 0x80000000u);  // monotone map
        }
        key[v] = u;
    }
    __syncthreads();
    // 4-pass radix select (MSB first) for the k-th largest key
    for (int pass = 0; pass < 4; ++pass) {
        int shift = 24 - 8 * pass;
        if (tid < 256) hist[tid] = 0;
        __syncthreads();
        unsigned maskHi = (pass == 0) ? 0u : (0xFFFFFFFFu << (32 - 8 * pass));
        unsigned pfx = sPrefix;
        for (int v = tid; v < n; v += 1024) {
            unsigned u = key[v];
            if ((u & maskHi) == (pfx & maskHi))
                atomicAdd(&hist[(u >> shift) & 255u], 1u);
        }
        __syncthreads();
        // suffix-inclusive scan: hist[b] <- sum_{b'>=b} hist[b']  (8 parallel rounds)
#pragma unroll
        for (int off = 1; off < 256; off <<= 1) {
            unsigned t = 0;
            if (tid < 256 && tid + off < 256) t = hist[tid + off];
            __syncthreads();
            if (tid < 256) hist[tid] += t;
            __syncthreads();
        }
        int rem = sRemain;           // snapshot BEFORE the single writer updates it
        __syncthreads();
        if (tid < 256) {
            unsigned Sb = hist[tid];
            unsigned Sb1 = (tid == 255) ? 0u : hist[tid + 1];
            if (Sb >= (unsigned)rem && Sb1 < (unsigned)rem) {   // exactly one bin matches
                sPrefix |= ((unsigned)tid) << shift;
                sRemain = rem - (int)Sb1;
            }
        }
        __syncthreads();
    }
    unsigned T = sPrefix;
    int take = sRemain;     // # of keys == T to keep (lowest indices)
    // pair prefix scan: hi32 = count(key>T), lo32 = count(key==T)
    for (int v = tid; v < SELSZ; v += 1024) {
        unsigned long long gt = (v < n && key[v] > T) ? 1ull : 0ull;
        unsigned long long eq = (v < n && key[v] == T) ? 1ull : 0ull;
        ps[v] = (gt << 32) | eq;
    }
    __syncthreads();
    for (int off = 1; off < SELSZ; off <<= 1) {
        unsigned long long t0 = 0, t1 = 0, t2 = 0;
        int v0 = tid, v1 = tid + 1024, v2 = tid + 2048;
        if (v0 >= off) t0 = ps[v0 - off];
        if (v1 >= off) t1 = ps[v1 - off];
        if (v2 >= off) t2 = ps[v2 - off];
        __syncthreads();
        ps[v0] += t0; ps[v1] += t1; ps[v2] += t2;
        __syncthreads();
    }
    for (int v = tid; v < n; v += 1024) {
        unsigned u = key[v];
        bool gt = u > T, eq = u == T;
        unsigned long long pv = ps[v];
        int p1 = (int)(pv >> 32) - (gt ? 1 : 0);          // exclusive gt count
        int p2 = (int)(pv & 0xFFFFFFFFull) - (eq ? 1 : 0); // exclusive eq count
        bool sel = gt || (eq && p2 < take);
        if (sel) perm[p1 + min(p2, take)] = v;
    }
}

__global__ void k_poolx(const float* __restrict__ h, const float* __restrict__ score,
                        const int* __restrict__ perm, int k, float* __restrict__ hp) {
    int t = blockIdx.x * blockDim.x + threadIdx.x;
    if (t >= k * HF) return;
    int i = t / HF, f = t % HF;
    int pi = perm[i];
    hp[t] = h[pi * HF + f] * score[pi];
}

// ---------------- bf16 gathers for the augment GEMM ----------------
// Rg[i*Kpad+m] = A[perm_i * nfull + m]
__global__ void k_gather_rg(const float* __restrict__ A, const int* __restrict__ perm,
                            int nfull, int M, int Kpad, unsigned short* __restrict__ Rg) {
    int t = blockIdx.x * blockDim.x + threadIdx.x;
    int kh = Kpad >> 1;
    if (t >= M * kh) return;
    int i = t / kh, m2 = (t - i * kh) * 2;
    const float* row = A + (size_t)perm[i] * nfull;
    float v0 = 0.f, v1 = 0.f;
    if (m2 + 1 < nfull) { float2 vv = *(const float2*)&row[m2]; v0 = vv.x; v1 = vv.y; }
    else if (m2 < nfull) { v0 = row[m2]; }
    unsigned pk = (unsigned)f2bf(v0) | ((unsigned)f2bf(v1) << 16);
    *(unsigned*)&Rg[(size_t)i * Kpad + m2] = pk;
}

// CgbT[j*Kpad+m] = A[m * nfull + perm_j] + 2*(m==perm_j)
__global__ __launch_bounds__(256) void k_gather_ct(
    const float* __restrict__ A, const int* __restrict__ perm,
    int nfull, int Nc, int Kpad, unsigned short* __restrict__ CgbT) {
    __shared__ float Ts[32][33];
    int j0 = blockIdx.x * 32, m0 = blockIdx.y * 32;
    int t = threadIdx.x;
    {   // read phase: m-major lanes, gathered columns of A
        int ml = t >> 3, jl4 = (t & 7) * 4;
        int m = m0 + ml;
#pragma unroll
        for (int e = 0; e < 4; ++e) {
            int j = j0 + jl4 + e;
            float v = 0.f;
            if (m < nfull && j < Nc) {
                int pj = perm[j];
                v = A[(size_t)m * nfull + pj];
                if (m == pj) v += 2.f;
            }
            Ts[jl4 + e][ml] = v;
        }
    }
    __syncthreads();
    {   // write phase: j-major lanes, coalesced ushort4 stores
        int jl = t >> 3, mq = (t & 7) * 4;
        unsigned lo = (unsigned)f2bf(Ts[jl][mq])     | ((unsigned)f2bf(Ts[jl][mq + 1]) << 16);
        unsigned hi = (unsigned)f2bf(Ts[jl][mq + 2]) | ((unsigned)f2bf(Ts[jl][mq + 3]) << 16);
        uint2 w; w.x = lo; w.y = hi;
        *(uint2*)&CgbT[(size_t)(j0 + jl) * Kpad + m0 + mq] = w;
    }
}

// ---------------- MFMA bf16 GEMM: C[i][j] = sum_m Rg[i][m]*CgbT[j][m]; diag=0 ----------------
__global__ __launch_bounds__(256) void k_pgemm_mfma(
    const unsigned short* __restrict__ Rg,    // M x Kpad (row-major)
    const unsigned short* __restrict__ CgbT,  // Npad x Kpad (row-major = B^T)
    float* __restrict__ C, int M, int Nc, int Kpad,
    float* __restrict__ degw) {
    __shared__ __align__(16) unsigned short As[64][40];
    __shared__ __align__(16) unsigned short Bs[64][40];
    int i0 = blockIdx.x * 64, j0 = blockIdx.y * 64;
    int tid = threadIdx.x;
    int lane = tid & 63, wid = tid >> 6;
    int wm = wid >> 1, wn = wid & 1;
    f32x4 acc[2][2] = {};
    int r = lane & 15, kq = lane >> 4;
    int srow = tid >> 2, scq = (tid & 3) * 8;
    for (int k0 = 0; k0 < Kpad; k0 += 32) {
        int gi = i0 + srow;
        bf16x8 av = {0, 0, 0, 0, 0, 0, 0, 0};
        if (gi < M) av = *(const bf16x8*)&Rg[(size_t)gi * Kpad + k0 + scq];
        bf16x8 bv = *(const bf16x8*)&CgbT[(size_t)(j0 + srow) * Kpad + k0 + scq];
        *(bf16x8*)&As[srow][scq] = av;
        *(bf16x8*)&Bs[srow][scq] = bv;
        __syncthreads();
        bf16x8 a0 = *(const bf16x8*)&As[wm * 32 + r][kq * 8];
        bf16x8 a1 = *(const bf16x8*)&As[wm * 32 + 16 + r][kq * 8];
        bf16x8 b0 = *(const bf16x8*)&Bs[wn * 32 + r][kq * 8];
        bf16x8 b1 = *(const bf16x8*)&Bs[wn * 32 + 16 + r][kq * 8];
        acc[0][0] = __builtin_amdgcn_mfma_f32_16x16x32_bf16(a0, b0, acc[0][0], 0, 0, 0);
        acc[0][1] = __builtin_amdgcn_mfma_f32_16x16x32_bf16(a0, b1, acc[0][1], 0, 0, 0);
        acc[1][0] = __builtin_amdgcn_mfma_f32_16x16x32_bf16(a1, b0, acc[1][0], 0, 0, 0);
        acc[1][1] = __builtin_amdgcn_mfma_f32_16x16x32_bf16(a1, b1, acc[1][1], 0, 0, 0);
        __syncthreads();
    }
#pragma unroll
    for (int nj = 0; nj < 2; ++nj) {
        int j = j0 + wn * 32 + nj * 16 + r;
        float csum = 0.f;
#pragma unroll
        for (int mi = 0; mi < 2; ++mi)
#pragma unroll
            for (int reg = 0; reg < 4; ++reg) {
                int i = i0 + wm * 32 + mi * 16 + kq * 4 + reg;
                if (i < M && j < Nc) {
                    float v = acc[mi][nj][reg];
                    if (i == j) v = 0.f;
                    C[(size_t)i * Nc + j] = v;
                    csum += v;
                }
            }
        if (j < Nc && csum != 0.f) atomicAdd(&degw[j], csum);
    }
}

// ---------------- unpool (concat skip) ----------------
__global__ void k_concat(const float* __restrict__ res, float* __restrict__ c, int n) {
    int t = blockIdx.x * blockDim.x + threadIdx.x;
    if (t >= n * HF) return;
    int v = t / HF, f = t % HF;
    c[v * (2 * HF) + f] = res[t];
    c[v * (2 * HF) + HF + f] = 0.f;
}

__global__ void k_upscat(const float* __restrict__ h, const int* __restrict__ perm,
                         float* __restrict__ c, int k) {
    int t = blockIdx.x * blockDim.x + threadIdx.x;
    if (t >= k * HF) return;
    int i = t / HF, f = t % HF;
    c[perm[i] * (2 * HF) + HF + f] = h[t];
}

// ---------------- final edge-based GCN (fout=3) ----------------
__global__ void k_finit(const float* __restrict__ fb, const float* __restrict__ selfw,
                        const float* __restrict__ Y3, float* __restrict__ out, int n) {
    int t = blockIdx.x * blockDim.x + threadIdx.x;
    if (t >= n * 3) return;
    int j = t / 3, f = t % 3;
    out[t] = fb[f] + selfw[j] * Y3[t];
}

__global__ void k_fedge(const int* __restrict__ ei, const float* __restrict__ ea,
                        const float* __restrict__ dinv, const float* __restrict__ Y3,
                        float* __restrict__ out) {
    int e = blockIdx.x * blockDim.x + threadIdx.x;
    if (e >= NE) return;
    int s = ei[e], d = ei[NE + e];
    float c = ea[e] * dinv[d];
    atomicAdd(&out[d * 3 + 0], c * Y3[s * 3 + 0]);
    atomicAdd(&out[d * 3 + 1], c * Y3[s * 3 + 1]);
    atomicAdd(&out[d * 3 + 2], c * Y3[s * 3 + 2]);
}

// ================= host orchestration =================
static inline int cdiv(int a, int b) { return (a + b - 1) / b; }

static void gcn_dense(hipStream_t st, const float* A, int n, const float* X, int fin,
                      const float* Wm, const float* bias, const float* dinv,
                      const float* selfw, float* Y, float* accum, float* out, bool gelu) {
    k_xw<<<cdiv(n * HF, 256), 256, 0, st>>>(X, Wm, dinv, n, fin, HF, Y);
    hipMemsetAsync(accum, 0, (size_t)n * HF * sizeof(float), st);
    int nsplit = cdiv(n, 192);
    k_aggS<<<dim3(cdiv(n, 16), nsplit), 256, 0, st>>>(A, Y, accum, n, 192);
    k_gcn_fin<<<cdiv(n * HF, 256), 256, 0, st>>>(accum, Y, dinv, selfw, bias, out, n,
                                                 gelu ? 1 : 0);
}

static void gcn_edge(hipStream_t st, const int* ei, const float* X, int fin,
                     const float* Wm, const float* bias, const float* dinv,
                     const float* selfw, float* Y, float* tmp, float* out, bool gelu) {
    k_xw<<<cdiv(N_NODES * HF, 256), 256, 0, st>>>(X, Wm, dinv, N_NODES, fin, HF, Y);
    hipMemsetAsync(tmp, 0, N_NODES * HF * sizeof(float), st);
    k_eagg<<<cdiv(NE * HF, 256), 256, 0, st>>>(ei, Y, tmp);
    k_gcn_fin<<<cdiv(N_NODES * HF, 256), 256, 0, st>>>(tmp, Y, dinv, selfw, bias, out,
                                                       N_NODES, gelu ? 1 : 0);
}

extern "C" void kernel_launch(void* const* d_in, const int* in_sizes, int n_in,
                              void* d_out, int out_size, void* d_ws, size_t ws_size,
                              hipStream_t stream) {
    const float* x   = (const float*)d_in[0];
    const int*   ei  = (const int*)d_in[1];
    const float* ea  = (const float*)d_in[2];
    const float* bng = (const float*)d_in[3];
    const float* bnb = (const float*)d_in[4];
    const float* dw0 = (const float*)d_in[5];
    const float* db0 = (const float*)d_in[6];
    const float* dw1 = (const float*)d_in[7];
    const float* db1 = (const float*)d_in[8];
    const float* dw2 = (const float*)d_in[9];
    const float* db2 = (const float*)d_in[10];
    const float* dw3 = (const float*)d_in[11];
    const float* db3 = (const float*)d_in[12];
    const float* p1  = (const float*)d_in[13];
    const float* p2  = (const float*)d_in[14];
    const float* p3  = (const float*)d_in[15];
    const float* uw1 = (const float*)d_in[16];
    const float* ub1 = (const float*)d_in[17];
    const float* uw2 = (const float*)d_in[18];
    const float* ub2 = (const float*)d_in[19];
    const float* uw3 = (const float*)d_in[20];
    const float* ub3 = (const float*)d_in[21];
    const float* fw  = (const float*)d_in[22];
    const float* fb  = (const float*)d_in[23];
    float* outp = (float*)d_out;

    // workspace layout (floats, 16B-aligned slots)
    float* W = (float*)d_ws;
    size_t o = 0;
    auto alloc = [&](size_t cnt) { float* p = W + o; o += (cnt + 3) & ~size_t(3); return p; };
    float* As0   = alloc(9000000);
    float* As1   = alloc(2250000);
    float* As2   = alloc(562500);
    float* A3    = alloc(140625);
    unsigned short* Rg  = (unsigned short*)alloc(2375000);   // 4.75M bf16
    unsigned short* Cgb = (unsigned short*)alloc(2375000);   // CgbT: Npad x Kpad
    float* xn    = alloc(15000);
    float* h0    = alloc(192000);
    float* h1    = alloc(96000);
    float* h2    = alloc(48000);
    float* h3    = alloc(24000);
    float* hu0   = alloc(48000);
    float* hu1   = alloc(96000);
    float* hu2   = alloc(192000);
    float* cbuf  = alloc(384000);
    float* Y     = alloc(192000);
    float* tmp   = alloc(192000);
    float* score = alloc(3000);
    float* degw  = alloc(3000);   // degw+dself contiguous: one combined memset
    float* dself = alloc(3000);
    float* dinvE = alloc(3000);  float* selfwE = alloc(3000);
    float* dinv1 = alloc(1500);  float* selfw1 = alloc(1500);
    float* dinv2 = alloc(750);   float* selfw2 = alloc(750);
    float* dinv3 = alloc(375);   float* selfw3 = alloc(375);
    float* dinvF = alloc(3000);  float* selfwF = alloc(3000);
    int* perm1 = (int*)alloc(1500);
    int* perm2 = (int*)alloc(750);
    int* perm3 = (int*)alloc(375);
    float* Y3  = alloc(9000);
    (void)ws_size; (void)in_sizes; (void)n_in; (void)out_size;

    // 1) BatchNorm
    k_bn<<<F_INF, 256, 0, stream>>>(x, bng, bnb, xn, N_NODES);

    // 2) A0 dense build + edge-based normalization for A0
    hipMemsetAsync(As0, 0, 9000000 * sizeof(float), stream);
    k_adj<<<cdiv(NE, 256), 256, 0, stream>>>(ei, As0, N_NODES);
    hipMemsetAsync(degw, 0, 2 * N_NODES * sizeof(float), stream);   // degw + dself
    k_edeg<<<cdiv(NE, 256), 256, 0, stream>>>(ei, degw, dself);
    k_dinv<<<cdiv(N_NODES, 256), 256, 0, stream>>>(degw, dself, N_NODES, dinvE, selfwE);

    // 3) first GCN (A0, edge aggregation) + gelu
    gcn_edge(stream, ei, xn, F_INF, dw0, db0, dinvE, selfwE, Y, tmp, h0, true);

    // 4) down path
    struct Lvl { const float* Ain; int n, k, Kpad, Npad; const float* hin;
                 const float* p; const float* Wd; const float* bd; int* perm;
                 float* Aout; float* hout; float* dinv; float* selfw; };
    Lvl lv[3] = {
        { As0, 3000, 1500, 3008, 1536, h0, p1, dw1, db1, perm1, As1, h1, dinv1, selfw1 },
        { As1, 1500,  750, 1504,  768, h1, p2, dw2, db2, perm2, As2, h2, dinv2, selfw2 },
        { As2,  750,  375,  768,  384, h2, p3, dw3, db3, perm3, A3,  h3, dinv3, selfw3 },
    };
    for (int L = 0; L < 3; ++L) {
        Lvl& v = lv[L];
        k_select<<<1, 1024, 0, stream>>>(v.hin, v.p, v.n, v.k, score, v.perm);
        k_poolx<<<cdiv(v.k * HF, 256), 256, 0, stream>>>(v.hin, score, v.perm, v.k, cbuf);
        k_gather_rg<<<cdiv(v.k * (v.Kpad >> 1), 256), 256, 0, stream>>>(
            v.Ain, v.perm, v.n, v.k, v.Kpad, Rg);
        k_gather_ct<<<dim3(v.Npad / 32, v.Kpad / 32), 256, 0, stream>>>(
            v.Ain, v.perm, v.n, v.k, v.Kpad, Cgb);
        hipMemsetAsync(degw, 0, v.k * sizeof(float), stream);
        k_pgemm_mfma<<<dim3(cdiv(v.k, 64), v.Npad / 64), 256, 0, stream>>>(
            Rg, Cgb, v.Aout, v.k, v.k, v.Kpad, degw);
        k_dinv_dense<<<cdiv(v.k, 256), 256, 0, stream>>>(degw, v.Aout, v.k, v.dinv, v.selfw);
        gcn_dense(stream, v.Aout, v.k, cbuf, HF, v.Wd, v.bd, v.dinv, v.selfw, Y, tmp,
                  v.hout, true);
    }

    // 5) up path
    struct Up { const float* A; int n, k; const int* perm; const float* res;
                const float* hprev; const float* Wu; const float* bu; float* out;
                const float* dinv; const float* selfw; bool g; bool edge; };
    Up up[3] = {
        { As2,  750,  375, perm3, h2, h3,  uw1, ub1, hu0, dinv2, selfw2, true,  false },
        { As1, 1500,  750, perm2, h1, hu0, uw2, ub2, hu1, dinv1, selfw1, true,  false },
        { As0, 3000, 1500, perm1, h0, hu1, uw3, ub3, hu2, dinvE, selfwE, false, true  },
    };
    for (int L = 0; L < 3; ++L) {
        Up& v = up[L];
        k_concat<<<cdiv(v.n * HF, 256), 256, 0, stream>>>(v.res, cbuf, v.n);
        k_upscat<<<cdiv(v.k * HF, 256), 256, 0, stream>>>(v.hprev, v.perm, cbuf, v.k);
        if (v.edge) {
            gcn_edge(stream, ei, cbuf, 2 * HF, v.Wu, v.bu, v.dinv, v.selfw, Y, tmp, v.out, v.g);
        } else {
            gcn_dense(stream, v.A, v.n, cbuf, 2 * HF, v.Wu, v.bu, v.dinv, v.selfw, Y, tmp,
                      v.out, v.g);
        }
    }

    // 6) final GCN with edge_attr weights (fout=3)
    hipMemsetAsync(degw, 0, 2 * N_NODES * sizeof(float), stream);   // degw + dself
    k_fdeg<<<cdiv(NE, 256), 256, 0, stream>>>(ei, ea, degw, dself);
    k_dinv<<<cdiv(N_NODES, 256), 256, 0, stream>>>(degw, dself, N_NODES, dinvF, selfwF);
    k_xw<<<cdiv(N_NODES * 3, 256), 256, 0, stream>>>(hu2, fw, dinvF, N_NODES, HF, 3, Y3);
    k_finit<<<cdiv(N_NODES * 3, 256), 256, 0, stream>>>(fb, selfwF, Y3, outp, N_NODES);
    k_fedge<<<cdiv(NE, 256), 256, 0, stream>>>(ei, ea, dinvF, Y3, outp);
}